// Round 19
// baseline (1698.303 us; speedup 1.0000x reference)
//
#include <hip/hip_runtime.h>
#include <hip/hip_fp16.h>
#include <math.h>

#define DIN   32
#define F1    64   // H1*C1
#define F2    64   // H2*C2
#define BN    128  // nodes per bucket

typedef _Float16 h2 __attribute__((ext_vector_type(2)));

template <class T, class F>
__device__ __forceinline__ T bitc(F f) { return __builtin_bit_cast(T, f); }

__device__ __forceinline__ unsigned f16pack(float a, float b) {
    h2 h = { (_Float16)a, (_Float16)b };
    return bitc<unsigned>(h);
}

// ---------------- dense-linear body (shared) --------------------------------
// 32-node x 128-output tile, 256 threads, 2x8 micro-tile (16 acc regs).
// xl stored FP16 (halves gat gather bytes); xr stays FP32.
template <int K>
__device__ __forceinline__ void lin_lr_body(int bid,
        const float* __restrict__ x,
        const float* __restrict__ Wl, const float* __restrict__ bl,
        const float* __restrict__ Wr, const float* __restrict__ br,
        __half* __restrict__ xl, float* __restrict__ xr, int n) {
    __shared__ float Ash[32][K + 4];
    __shared__ float Wsh[K][128];
    const int t = threadIdx.x;
    const int node0 = bid * 32;

    for (int idx = t; idx < 32 * (K / 4); idx += 256) {
        int m = idx / (K / 4), kq = idx % (K / 4);
        float4 v = make_float4(0.f, 0.f, 0.f, 0.f);
        if (node0 + m < n) v = ((const float4*)(x + (size_t)(node0 + m) * K))[kq];
        *(float4*)&Ash[m][kq * 4] = v;
    }
    for (int idx = t; idx < K * 32; idx += 256) {
        int k = idx / 32, j4 = idx % 32;
        float4 v = (j4 < 16) ? ((const float4*)(Wl + (size_t)k * 64))[j4]
                             : ((const float4*)(Wr + (size_t)k * 64))[j4 - 16];
        *(float4*)&Wsh[k][j4 * 4] = v;
    }
    __syncthreads();

    const int ty = t >> 4;
    const int tx = t & 15;
    float acc0[8], acc1[8];
#pragma unroll
    for (int j = 0; j < 8; j++) { acc0[j] = 0.f; acc1[j] = 0.f; }

#pragma unroll 4
    for (int k = 0; k < K; k++) {
        float a0 = Ash[ty * 2 + 0][k];
        float a1 = Ash[ty * 2 + 1][k];
        float4 w0 = *(const float4*)&Wsh[k][tx * 8];
        float4 w1 = *(const float4*)&Wsh[k][tx * 8 + 4];
        acc0[0] += a0 * w0.x; acc0[1] += a0 * w0.y;
        acc0[2] += a0 * w0.z; acc0[3] += a0 * w0.w;
        acc0[4] += a0 * w1.x; acc0[5] += a0 * w1.y;
        acc0[6] += a0 * w1.z; acc0[7] += a0 * w1.w;
        acc1[0] += a1 * w0.x; acc1[1] += a1 * w0.y;
        acc1[2] += a1 * w0.z; acc1[3] += a1 * w0.w;
        acc1[4] += a1 * w1.x; acc1[5] += a1 * w1.y;
        acc1[6] += a1 * w1.z; acc1[7] += a1 * w1.w;
    }

    const float* bsrc = (tx < 8) ? bl : br;
    int jb = (tx < 8) ? tx * 8 : (tx - 8) * 8;
    float4 b0 = ((const float4*)(bsrc + jb))[0];
    float4 b1 = ((const float4*)(bsrc + jb))[1];
#pragma unroll
    for (int m = 0; m < 2; m++) {
        int node = node0 + ty * 2 + m;
        if (node >= n) continue;
        const float* ac = (m == 0) ? acc0 : acc1;
        float o0 = ac[0] + b0.x, o1 = ac[1] + b0.y;
        float o2 = ac[2] + b0.z, o3 = ac[3] + b0.w;
        float o4 = ac[4] + b1.x, o5 = ac[5] + b1.y;
        float o6 = ac[6] + b1.z, o7 = ac[7] + b1.w;
        if (tx < 8) {
            uint4 pk;
            pk.x = f16pack(o0, o1); pk.y = f16pack(o2, o3);
            pk.z = f16pack(o4, o5); pk.w = f16pack(o6, o7);
            *((uint4*)(xl + (size_t)node * 64 + jb)) = pk;
        } else {
            ((float4*)(xr + (size_t)node * 64 + jb))[0] = make_float4(o0, o1, o2, o3);
            ((float4*)(xr + (size_t)node * 64 + jb))[1] = make_float4(o4, o5, o6, o7);
        }
    }
}

// ---------------- K1: count + reserve + scatter (512 chunks) || lin1 --------
// R19: 512 chunks (R18's 256 were latency-bound at low occupancy). Buckets of
// 128 nodes (NBK = ceil(N/128) = 391). Record: lo = src | (dst&127)<<24,
// hi = fp16(ea0)|fp16(ea1)<<16. inter is bucket-partitioned, UNSORTED within
// bucket — the scatter-gat consumes it directly (no bucket_csr pass).
__global__ __launch_bounds__(256, 2)
void fused_csr_lin1(const int* __restrict__ dstr, const int* __restrict__ srcr,
                    const float* __restrict__ ea, int* __restrict__ cursor,
                    int2* __restrict__ inter,
                    int E, int Ec, int NBK, int cap, int gridLin,
                    const float* __restrict__ x,
                    const float* __restrict__ Wl, const float* __restrict__ bl,
                    const float* __restrict__ Wr, const float* __restrict__ br,
                    __half* __restrict__ xl, float* __restrict__ xr, int n) {
    __shared__ int hist[512];
    __shared__ int base[512];
    if ((int)blockIdx.x < gridLin) {
        lin_lr_body<DIN>(blockIdx.x, x, Wl, bl, Wr, br, xl, xr, n);
        return;
    }
    const int blk = blockIdx.x - gridLin;
    const int t = threadIdx.x;
    hist[t] = 0; hist[t + 256] = 0;
    __syncthreads();
    const int s0 = blk * Ec, s1 = min(E, s0 + Ec);
    for (int e = s0 + t; e < s1; e += 256)
        atomicAdd(&hist[dstr[e] >> 7], 1);
    __syncthreads();
    for (int b = t; b < NBK; b += 256) {
        int h = hist[b];
        base[b] = b * cap + (h ? atomicAdd(&cursor[b], h) : 0);
    }
    __syncthreads();
    hist[t] = 0; hist[t + 256] = 0;
    __syncthreads();
    for (int e = s0 + t; e < s1; e += 256) {
        int d = dstr[e];
        int b = d >> 7;
        int lr = atomicAdd(&hist[b], 1);
        float2 v = ((const float2*)ea)[e];
        int2 r;
        r.x = srcr[e] | ((d & 127) << 24);
        r.y = (int)f16pack(v.x, v.y);
        inter[base[b] + lr] = r;
    }
}

__global__ __launch_bounds__(256, 2)
void lin_lr_tiled64(const float* __restrict__ x,
                    const float* __restrict__ Wl, const float* __restrict__ bl,
                    const float* __restrict__ Wr, const float* __restrict__ br,
                    __half* __restrict__ xl, float* __restrict__ xr, int n) {
    lin_lr_body<F1>(blockIdx.x, x, Wl, bl, Wr, br, xl, xr, n);
}

// ---------------- scatter-gat: per-bucket GATv2, LDS-atomic accumulate ------
// R19: max-free softmax is ORDER-INDEPENDENT -> no sorted CSR needed. One
// block per 128-node bucket; 32 16-lane groups each stream edges from inter
// (coalesced contiguous records) and scatter p/p*xv into LDS float atomics.
// Bank padding: acc row stride 68 floats, xr row stride 17 uint2 (breaks the
// dst*64%32==0 alias). Finalize per node: self-loop (ea mean from LDS sums),
// divide, bias, relu, store h (or fused heads). Replaces bucket_csr + sorted
// edges + rse/la2 entirely: 4 launches total.
template <int H, int C, bool FUSE_HEADS>
__global__ __launch_bounds__(512, 4)
void gat_scatter(const __half* __restrict__ xl, const float* __restrict__ xr,
                 const int* __restrict__ cursor, const int2* __restrict__ inter,
                 const float* __restrict__ We, const float* __restrict__ att,
                 const float* __restrict__ bias, float* __restrict__ hout,
                 const float* __restrict__ wa, const float* __restrict__ ba,
                 const float* __restrict__ wc, const float* __restrict__ bcv,
                 const float* __restrict__ ls, float* __restrict__ pout,
                 int n, int cap) {
    constexpr int LPH = C / 4;
    __shared__ float accs[BN * 68];
    __shared__ uint2 xrh[BN * 17];
    __shared__ float dens[BN * 4];
    __shared__ float eass[BN * 2];
    __shared__ int   cnts[BN];
    const int b = blockIdx.x, t = threadIdx.x;
    const int q = t & 15;          // feature quad within group
    const int gid = t >> 4;        // group 0..31
    const int node0 = b * BN;

    if (FUSE_HEADS && b == 0 && t < 2)
        pout[(size_t)n * 2 + t] = expf(ls[t]);

    for (int i = t; i < BN * 68; i += 512) accs[i] = 0.f;
    for (int i = t; i < BN * 4; i += 512) dens[i] = 0.f;
    for (int i = t; i < BN * 2; i += 512) eass[i] = 0.f;
    if (t < BN) cnts[t] = 0;
    for (int i = t; i < BN * 16; i += 512) {        // stage xr -> fp16 LDS
        int nd = i >> 4, j = i & 15;
        int node = node0 + nd;
        uint2 v = make_uint2(0u, 0u);
        if (node < n) {
            float4 f = ((const float4*)(xr + (size_t)node * 64))[j];
            v.x = f16pack(f.x, f.y);
            v.y = f16pack(f.z, f.w);
        }
        xrh[nd * 17 + j] = v;
    }
    __syncthreads();

    const uint2* xlh = (const uint2*)xl;
    float4 avf = ((const float4*)att)[q];
    const float LOG2E = 1.4426950408889634f;
    avf.x *= LOG2E; avf.y *= LOG2E; avf.z *= LOG2E; avf.w *= LOG2E;
    const float4 we0f = ((const float4*)We)[q];
    const float4 we1f = ((const float4*)(We + 64))[q];
    const h2 we0h01 = { (_Float16)we0f.x, (_Float16)we0f.y };
    const h2 we0h23 = { (_Float16)we0f.z, (_Float16)we0f.w };
    const h2 we1h01 = { (_Float16)we1f.x, (_Float16)we1f.y };
    const h2 we1h23 = { (_Float16)we1f.z, (_Float16)we1f.w };
    const h2 avh01  = { (_Float16)avf.x, (_Float16)avf.y };
    const h2 avh23  = { (_Float16)avf.z, (_Float16)avf.w };
    const h2 lk = { (_Float16)0.2f, (_Float16)0.2f };

    const int ecnt = cursor[b];
    const int bstart = b * cap;

    if (ecnt > 0) {
        int k = gid;
        int2 rc = inter[bstart + min(k, ecnt - 1)];
        uint2 xc = xlh[((((unsigned)rc.x) & 0xFFFFFFu) << 4) + q];
        while (k < ecnt) {
            int kn = k + 32;
            int2 rn = inter[bstart + min(kn, ecnt - 1)];
            uint2 xn = xlh[((((unsigned)rn.x) & 0xFFFFFFu) << 4) + q];

            unsigned ebits = (unsigned)rc.y;
            int nd = ((unsigned)rc.x) >> 24;
            h2 ea0h = bitc<h2>((ebits & 0xFFFFu) | (ebits << 16));
            h2 ea1h = bitc<h2>((ebits >> 16) | (ebits & 0xFFFF0000u));
            uint2 xriu = xrh[nd * 17 + q];
            h2 xv01 = bitc<h2>(xc.x), xv23 = bitc<h2>(xc.y);
            h2 z01 = xv01 + (ea0h * we0h01 + (ea1h * we1h01 + bitc<h2>(xriu.x)));
            h2 z23 = xv23 + (ea0h * we0h23 + (ea1h * we1h23 + bitc<h2>(xriu.y)));
            z01 = __builtin_elementwise_max(z01, z01 * lk);
            z23 = __builtin_elementwise_max(z23, z23 * lk);
            float l = __builtin_amdgcn_fdot2(z01, avh01,
                      __builtin_amdgcn_fdot2(z23, avh23, 0.f, false), false);
#pragma unroll
            for (int m = 1; m < LPH; m <<= 1) l += __shfl_xor(l, m, 64);
            float p = exp2f(l);
            atomicAdd(&accs[nd * 68 + 4 * q + 0], p * (float)xv01[0]);
            atomicAdd(&accs[nd * 68 + 4 * q + 1], p * (float)xv01[1]);
            atomicAdd(&accs[nd * 68 + 4 * q + 2], p * (float)xv23[0]);
            atomicAdd(&accs[nd * 68 + 4 * q + 3], p * (float)xv23[1]);
            if ((q & (LPH - 1)) == 0)
                atomicAdd(&dens[nd * 4 + q / LPH], p);
            if (q == 0) {
                atomicAdd(&eass[nd * 2 + 0], (float)ea0h[0]);
                atomicAdd(&eass[nd * 2 + 1], (float)ea1h[0]);
                atomicAdd(&cnts[nd], 1);
            }
            rc = rn; xc = xn; k = kn;
        }
    }
    __syncthreads();

    const float4 bv = ((const float4*)bias)[q];
#pragma unroll
    for (int pass = 0; pass < 4; pass++) {
        int nd = pass * 32 + gid;
        int node = node0 + nd;
        if (node >= n) continue;       // uniform within each 16-lane group
        uint2 xpi = xlh[(((unsigned)node) << 4) + q];
        h2 xi01 = bitc<h2>(xpi.x), xi23 = bitc<h2>(xpi.y);
        float4 xlv = make_float4((float)xi01[0], (float)xi01[1],
                                 (float)xi23[0], (float)xi23[1]);
        uint2 xriu = xrh[nd * 17 + q];
        h2 xr01 = bitc<h2>(xriu.x), xr23 = bitc<h2>(xriu.y);
        int c = cnts[nd];
        float inv = c ? 1.0f / (float)c : 0.f;
        float la0 = eass[nd * 2] * inv, la1 = eass[nd * 2 + 1] * inv;
        float z0 = xlv.x + fmaf(la0, we0f.x, fmaf(la1, we1f.x, (float)xr01[0]));
        float z1 = xlv.y + fmaf(la0, we0f.y, fmaf(la1, we1f.y, (float)xr01[1]));
        float z2 = xlv.z + fmaf(la0, we0f.z, fmaf(la1, we1f.z, (float)xr23[0]));
        float z3 = xlv.w + fmaf(la0, we0f.w, fmaf(la1, we1f.w, (float)xr23[1]));
        z0 = fmaxf(z0, 0.2f * z0);
        z1 = fmaxf(z1, 0.2f * z1);
        z2 = fmaxf(z2, 0.2f * z2);
        z3 = fmaxf(z3, 0.2f * z3);
        float l = fmaf(z0, avf.x, fmaf(z1, avf.y, fmaf(z2, avf.z, z3 * avf.w)));
#pragma unroll
        for (int m = 1; m < LPH; m <<= 1) l += __shfl_xor(l, m, 64);
        float p = exp2f(l);
        float rd = 1.0f / (dens[nd * 4 + q / LPH] + p);
        float4 o;
        o.x = fmaxf(fmaf(fmaf(p, xlv.x, accs[nd * 68 + 4 * q + 0]), rd, bv.x), 0.f);
        o.y = fmaxf(fmaf(fmaf(p, xlv.y, accs[nd * 68 + 4 * q + 1]), rd, bv.y), 0.f);
        o.z = fmaxf(fmaf(fmaf(p, xlv.z, accs[nd * 68 + 4 * q + 2]), rd, bv.z), 0.f);
        o.w = fmaxf(fmaf(fmaf(p, xlv.w, accs[nd * 68 + 4 * q + 3]), rd, bv.w), 0.f);

        if (!FUSE_HEADS) {
            ((float4*)(hout + (size_t)node * 64))[q] = o;
        } else {
            float4 wa01 = ((const float4*)wa)[q * 2];
            float4 wa23 = ((const float4*)wa)[q * 2 + 1];
            float4 wcv  = ((const float4*)wc)[q];
            float d0 = o.x * wa01.x + o.y * wa01.z + o.z * wa23.x + o.w * wa23.z;
            float d1 = o.x * wa01.y + o.y * wa01.w + o.z * wa23.y + o.w * wa23.w;
            float d2 = o.x * wcv.x + o.y * wcv.y + o.z * wcv.z + o.w * wcv.w;
#pragma unroll
            for (int m = 1; m < 16; m <<= 1) {
                d0 += __shfl_xor(d0, m, 64);
                d1 += __shfl_xor(d1, m, 64);
                d2 += __shfl_xor(d2, m, 64);
            }
            if (q == 0) {
                pout[(size_t)node * 2 + 0] = tanhf(d0 + ba[0]);
                pout[(size_t)node * 2 + 1] = tanhf(d1 + ba[1]);
                pout[(size_t)n * 2 + 2 + node] = d2 + bcv[0];
            }
        }
    }
}

// ---------------- launch ---------------------------------------------------

extern "C" void kernel_launch(void* const* d_in, const int* in_sizes, int n_in,
                              void* d_out, int out_size, void* d_ws, size_t ws_size,
                              hipStream_t stream) {
    const float* x    = (const float*)d_in[0];
    const int*   ei   = (const int*)  d_in[1];
    const float* ea   = (const float*)d_in[2];
    const float* w1l  = (const float*)d_in[3];
    const float* b1l  = (const float*)d_in[4];
    const float* w1r  = (const float*)d_in[5];
    const float* b1r  = (const float*)d_in[6];
    const float* w1e  = (const float*)d_in[7];
    const float* att1 = (const float*)d_in[8];
    const float* bias1= (const float*)d_in[9];
    const float* w2l  = (const float*)d_in[10];
    const float* b2l  = (const float*)d_in[11];
    const float* w2r  = (const float*)d_in[12];
    const float* b2r  = (const float*)d_in[13];
    const float* w2e  = (const float*)d_in[14];
    const float* att2 = (const float*)d_in[15];
    const float* bias2= (const float*)d_in[16];
    const float* wa   = (const float*)d_in[17];
    const float* ba   = (const float*)d_in[18];
    const float* wc   = (const float*)d_in[19];
    const float* bcv  = (const float*)d_in[20];
    const float* ls   = (const float*)d_in[21];

    const int N = in_sizes[0] / DIN;
    const int E = in_sizes[2] / 2;
    const int* srcr = ei;
    const int* dstr = ei + E;

    const int NBK = (N + BN - 1) / BN;       // 391 buckets of 128 nodes
    const int NCH = 512;                     // CSR chunks
    const int Ec = (E + NCH - 1) / NCH;
    int cap = (E + NBK - 1) / NBK;           // bucket capacity, 1.25x mean
    cap = ((cap + cap / 4) + 63) & ~63;

    char* p = (char*)d_ws;
    auto alloc = [&](size_t bytes) -> void* {
        void* r = (void*)p;
        p += (bytes + 255) & ~(size_t)255;
        return r;
    };
    int*    cursor = (int*)   alloc(512 * 4);
    int2*   inter  = (int2*)  alloc(((size_t)NBK * cap + 64) * 8);
    __half* xl     = (__half*)alloc((size_t)N * F1 * 2);
    float*  xr     = (float*) alloc((size_t)N * F1 * 4);
    float*  h1     = (float*) alloc((size_t)N * F1 * 4);
    (void)ws_size; (void)n_in; (void)out_size;

    (void)hipMemsetAsync(cursor, 0, 512 * 4, stream);

    const int TB = 256;
    int gridGemm = (N + 31) / 32;

    fused_csr_lin1<<<gridGemm + NCH, TB, 0, stream>>>(
        dstr, srcr, ea, cursor, inter, E, Ec, NBK, cap, gridGemm,
        x, w1l, b1l, w1r, b1r, xl, xr, N);
    gat_scatter<4, 16, false><<<NBK, 512, 0, stream>>>(
        xl, xr, cursor, inter, w1e, att1, bias1, h1,
        nullptr, nullptr, nullptr, nullptr, nullptr, nullptr, N, cap);
    lin_lr_tiled64<<<gridGemm, TB, 0, stream>>>(h1, w2l, b2l, w2r, b2r, xl, xr, N);
    gat_scatter<2, 32, true><<<NBK, 512, 0, stream>>>(
        xl, xr, cursor, inter, w2e, att2, bias2, nullptr,
        wa, ba, wc, bcv, ls, (float*)d_out, N, cap);
}